// Round 7
// baseline (28.359 us; speedup 1.0000x reference)
//
#include <hip/hip_runtime.h>
#include <hip/hip_bf16.h>

#define B_SZ   256
#define N_IN   128
#define F_IN   64
#define G_SZ   128
#define F_OUT  64
#define S_SZ   16
#define K_TOT  1024   // S_SZ * F_IN

#define M_TILE 64
#define BK     64
#define NSTEP  16     // K_TOT / BK
#define THREADS 256   // 4 waves: wave grid 2 (M) x 2 (N), 32x32 tiles
// grid = 128 g * 4 m-tiles = 512 blocks = 2 independent blocks/CU.
// Co-resident blocks blk and blk+256 share g -> same W stream (L1 reuse),
// independent barrier groups cover each other's stalls.

// LDS row stride in bf16 elements: 64 + 8 pad = 72 (144 B rows): <=2-way
// bank aliasing on ds_read_b128 (free per m136)
#define LDSTRIDE 72

typedef __attribute__((ext_vector_type(8))) short short8;  // 8 bf16
typedef __attribute__((ext_vector_type(4))) float f32x4;
typedef unsigned short u16;
typedef unsigned int   u32;

static __device__ __forceinline__ u32 packbf2(float a, float b) {
    // low 16 = a, high 16 = b (RNE); compiler emits v_cvt_pk_bf16_f32
    __hip_bfloat162 h = __float22bfloat162_rn(make_float2(a, b));
    union { __hip_bfloat162 h; u32 u; } c; c.h = h;
    return c.u;
}

__global__ __launch_bounds__(THREADS, 2)
void sparse_linear_kernel(const float* __restrict__ x,
                          const int*   __restrict__ idx,
                          const float* __restrict__ W,
                          const float* __restrict__ bias,
                          float*       __restrict__ out)
{
    __shared__ u16 Alds[2][M_TILE * LDSTRIDE];
    __shared__ u16 Wlds[2][F_OUT * LDSTRIDE];

    const int blk   = blockIdx.x;
    const int g     = blk & 127;   // same-g blocks 128 apart -> same XCD L2
    const int mt    = blk >> 7;    // 0..3
    const int bbase = mt * M_TILE;

    const int tid  = threadIdx.x;
    const int wave = tid >> 6;
    const int lane = tid & 63;
    const int wr   = wave >> 1;    // 0..1 (M, 32 rows)
    const int wc   = wave & 1;     // 0..1 (N, 32 cols)
    const int lmod = lane & 15;
    const int ldiv = lane >> 4;

    // ---- staging coords: id = tid + i*256 in 0..1023 -> r = id>>4, f = (id&15)*4
    const float* aptr[4];
    const float* wptr[4];
    int lofs[4];
    #pragma unroll
    for (int i = 0; i < 4; ++i) {
        int id = tid + i * THREADS;
        int r  = id >> 4;                  // 0..63
        int f  = (id & 15) << 2;           // float col
        aptr[i] = x + (size_t)(bbase + r) * (N_IN * F_IN) + f;
        wptr[i] = W + (size_t)g * (F_OUT * K_TOT) + (size_t)r * K_TOT + f;
        lofs[i] = r * (LDSTRIDE * 2) + f * 2;
    }

    int rows[NSTEP];
    #pragma unroll
    for (int s = 0; s < NSTEP; ++s) rows[s] = idx[g * S_SZ + s];  // uniform -> SGPR

    f32x4  acc[2][2] = {};
    float4 ra[3][4], rw[3][4];             // depth-3 register sets

    #define LOADT(t, s)                                                        \
        {                                                                      \
            const int row = rows[t];                                           \
            _Pragma("unroll")                                                  \
            for (int i = 0; i < 4; ++i)                                        \
                ra[s][i] = *reinterpret_cast<const float4*>(aptr[i] + row * F_IN); \
            _Pragma("unroll")                                                  \
            for (int i = 0; i < 4; ++i)                                        \
                rw[s][i] = *reinterpret_cast<const float4*>(wptr[i] + (t) * BK);   \
        }

    #define STORET(s, buf)                                                     \
        {                                                                      \
            _Pragma("unroll")                                                  \
            for (int i = 0; i < 4; ++i) {                                      \
                uint2 p;                                                       \
                p.x = packbf2(ra[s][i].x, ra[s][i].y);                         \
                p.y = packbf2(ra[s][i].z, ra[s][i].w);                         \
                *reinterpret_cast<uint2*>(                                     \
                    reinterpret_cast<char*>(Alds[buf]) + lofs[i]) = p;         \
            }                                                                  \
            _Pragma("unroll")                                                  \
            for (int i = 0; i < 4; ++i) {                                      \
                uint2 p;                                                       \
                p.x = packbf2(rw[s][i].x, rw[s][i].y);                         \
                p.y = packbf2(rw[s][i].z, rw[s][i].w);                         \
                *reinterpret_cast<uint2*>(                                     \
                    reinterpret_cast<char*>(Wlds[buf]) + lofs[i]) = p;         \
            }                                                                  \
        }

    #define COMPUTE(buf)                                                       \
        {                                                                      \
            _Pragma("unroll")                                                  \
            for (int ks = 0; ks < 2; ++ks) {                                   \
                const int kb = ks * 32 + (ldiv << 3);                          \
                short8 a[2], bfr[2];                                           \
                _Pragma("unroll")                                              \
                for (int mi = 0; mi < 2; ++mi)                                 \
                    a[mi] = *reinterpret_cast<const short8*>(                  \
                        reinterpret_cast<const char*>(Alds[buf]) +             \
                        (wr * 32 + mi * 16 + lmod) * (LDSTRIDE * 2) + kb * 2); \
                _Pragma("unroll")                                              \
                for (int ni = 0; ni < 2; ++ni)                                 \
                    bfr[ni] = *reinterpret_cast<const short8*>(                \
                        reinterpret_cast<const char*>(Wlds[buf]) +             \
                        (wc * 32 + ni * 16 + lmod) * (LDSTRIDE * 2) + kb * 2); \
                _Pragma("unroll")                                              \
                for (int mi = 0; mi < 2; ++mi)                                 \
                    _Pragma("unroll")                                          \
                    for (int ni = 0; ni < 2; ++ni)                             \
                        acc[mi][ni] = __builtin_amdgcn_mfma_f32_16x16x32_bf16( \
                            a[mi], bfr[ni], acc[mi][ni], 0, 0, 0);             \
            }                                                                  \
        }

    // Barrier WITHOUT the compiler's vmcnt(0) drain: drain only LDS ops
    // (own ds_writes visible; own ds_reads of the buffer about to be
    // overwritten completed). Global loads stay in flight.
    #define ROLL_BARRIER()                                                     \
        {                                                                      \
            asm volatile("s_waitcnt lgkmcnt(0)" ::: "memory");                 \
            __builtin_amdgcn_s_barrier();                                      \
            asm volatile("" ::: "memory");                                     \
        }

    // ---- prologue: 3 load sets in flight, buffer 0 staged ----
    LOADT(0, 0);
    LOADT(1, 1);
    LOADT(2, 2);
    STORET(0, 0);          // counted wait: only set-0's 8 loads (16 in flight)
    ROLL_BARRIER();

    // ---- main loop: rolling depth-3 pipeline; vmcnt never drained to 0 ----
    #pragma unroll
    for (int t = 0; t < NSTEP; ++t) {
        if (t + 3 < NSTEP) LOADT(t + 3, t % 3);          // issue early
        COMPUTE(t & 1);
        if (t + 1 < NSTEP) {
            STORET((t + 1) % 3, (t + 1) & 1);            // waits set t+1 only
            ROLL_BARRIER();
        }
    }

    // ---- epilogue: C frag col = lane&15, row = (lane>>4)*4 + r ----
    const int rowbase = bbase + wr * 32 + (ldiv << 2);
    #pragma unroll
    for (int ni = 0; ni < 2; ++ni) {
        const int o  = wc * 32 + ni * 16 + lmod;
        const float bv = bias[g * F_OUT + o];
        #pragma unroll
        for (int mi = 0; mi < 2; ++mi) {
            #pragma unroll
            for (int r = 0; r < 4; ++r) {
                const int brow = rowbase + mi * 16 + r;
                out[(size_t)brow * (G_SZ * F_OUT) + g * F_OUT + o] = acc[mi][ni][r] + bv;
            }
        }
    }
}

extern "C" void kernel_launch(void* const* d_in, const int* in_sizes, int n_in,
                              void* d_out, int out_size, void* d_ws, size_t ws_size,
                              hipStream_t stream) {
    const float* x    = (const float*)d_in[0];
    const int*   idx  = (const int*)d_in[1];
    const float* W    = (const float*)d_in[2];
    const float* bias = (const float*)d_in[3];
    float*       out  = (float*)d_out;

    sparse_linear_kernel<<<dim3(G_SZ * (B_SZ / M_TILE)), dim3(THREADS), 0, stream>>>(
        x, idx, W, bias, out);
}

// Round 8
// 24.800 us; speedup vs baseline: 1.1435x; 1.1435x over previous
//
#include <hip/hip_runtime.h>
#include <hip/hip_bf16.h>

#define B_SZ   256
#define N_IN   128
#define F_IN   64
#define G_SZ   128
#define F_OUT  64
#define S_SZ   16
#define K_TOT  1024   // S_SZ * F_IN

#define M_TILE 128
#define BK     128    // 2 gathered rows per K-step
#define NSTEP  8      // K_TOT / BK
#define THREADS 512   // 8 waves: wave grid 4 (M) x 2 (N)

// LDS row stride in bf16 elements: 128 + 8 pad = 136 (272 B = 68 dw == 4 mod 32):
// frag ds_read_b128 16-lane phase groups land 2 lanes/bank (free per m136)
#define LDSTRIDE 136

typedef __attribute__((ext_vector_type(8))) short short8;  // 8 bf16
typedef __attribute__((ext_vector_type(4))) float f32x4;
typedef unsigned short u16;
typedef unsigned int   u32;

static __device__ __forceinline__ u32 packbf2(float a, float b) {
    // low 16 = a, high 16 = b (RNE); compiler emits v_cvt_pk_bf16_f32
    __hip_bfloat162 h = __float22bfloat162_rn(make_float2(a, b));
    union { __hip_bfloat162 h; u32 u; } c; c.h = h;
    return c.u;
}

__global__ __launch_bounds__(THREADS)
void sparse_linear_kernel(const float* __restrict__ x,
                          const int*   __restrict__ idx,
                          const float* __restrict__ W,
                          const float* __restrict__ bias,
                          float*       __restrict__ out)
{
    __shared__ u16 Alds[2][M_TILE * LDSTRIDE];   // 2 x 34.8 KB
    __shared__ u16 Wlds[2][F_OUT * LDSTRIDE];    // 2 x 17.4 KB   (total 104.5 KB)

    const int blk   = blockIdx.x;
    const int g     = blk & 127;   // blk, blk+128 share W[g]; 128%8==0 -> same XCD
    const int mt    = blk >> 7;
    const int bbase = mt * M_TILE;

    const int tid  = threadIdx.x;
    const int wave = tid >> 6;
    const int lane = tid & 63;
    const int wr   = wave >> 1;    // 0..3 (M, 32 rows)
    const int wc   = wave & 1;     // 0..1 (N, 32 cols)
    const int lmod = lane & 15;
    const int ldiv = lane >> 4;

    // ---- A staging: 8 chunks/thread, id = tid + i*512 in 0..4095 ----
    // chunk: m = id>>5 (0..127), kq = id&31 (4-float column chunk)
    //   k_local = kq*4; kq<16 -> s-half 0, f=kq*4; kq>=16 -> half 1, f=(kq-16)*4
    const float* aptr[8]; int lofsA[8], halfA[8];
    #pragma unroll
    for (int i = 0; i < 8; ++i) {
        int id = tid + i * THREADS;
        int m  = id >> 5;
        int kq = id & 31;
        halfA[i] = kq >> 4;
        aptr[i]  = x + (size_t)(bbase + m) * (N_IN * F_IN) + (kq & 15) * 4;
        lofsA[i] = m * (LDSTRIDE * 2) + kq * 8;
    }
    // ---- W staging: 4 chunks/thread, id in 0..2047 ----
    const float* wptr[4]; int lofsW[4];
    #pragma unroll
    for (int i = 0; i < 4; ++i) {
        int id = tid + i * THREADS;
        int o  = id >> 5;                  // 0..63
        int kq = id & 31;
        wptr[i]  = W + (size_t)g * (F_OUT * K_TOT) + (size_t)o * K_TOT + kq * 4;
        lofsW[i] = o * (LDSTRIDE * 2) + kq * 8;
    }

    int rows[S_SZ];
    #pragma unroll
    for (int s = 0; s < S_SZ; ++s) rows[s] = idx[g * S_SZ + s];  // uniform -> SGPR

    f32x4  acc[2][2] = {};
    float4 ra[2][8], rw[2][4];             // depth-2 register sets

    #define LOADT(t, s)                                                        \
        {                                                                      \
            _Pragma("unroll")                                                  \
            for (int i = 0; i < 8; ++i)                                        \
                ra[s][i] = *reinterpret_cast<const float4*>(                   \
                    aptr[i] + rows[2 * (t) + halfA[i]] * F_IN);                \
            _Pragma("unroll")                                                  \
            for (int i = 0; i < 4; ++i)                                        \
                rw[s][i] = *reinterpret_cast<const float4*>(wptr[i] + (t) * BK); \
        }

    #define STORET(s, buf)                                                     \
        {                                                                      \
            _Pragma("unroll")                                                  \
            for (int i = 0; i < 8; ++i) {                                      \
                uint2 p;                                                       \
                p.x = packbf2(ra[s][i].x, ra[s][i].y);                         \
                p.y = packbf2(ra[s][i].z, ra[s][i].w);                         \
                *reinterpret_cast<uint2*>(                                     \
                    reinterpret_cast<char*>(Alds[buf]) + lofsA[i]) = p;        \
            }                                                                  \
            _Pragma("unroll")                                                  \
            for (int i = 0; i < 4; ++i) {                                      \
                uint2 p;                                                       \
                p.x = packbf2(rw[s][i].x, rw[s][i].y);                         \
                p.y = packbf2(rw[s][i].z, rw[s][i].w);                         \
                *reinterpret_cast<uint2*>(                                     \
                    reinterpret_cast<char*>(Wlds[buf]) + lofsW[i]) = p;        \
            }                                                                  \
        }

    #define COMPUTE(buf)                                                       \
        {                                                                      \
            _Pragma("unroll")                                                  \
            for (int ks = 0; ks < 4; ++ks) {                                   \
                const int kb2 = ks * 64 + ldiv * 16;      /* byte col */       \
                short8 a[2], bfr[2];                                           \
                _Pragma("unroll")                                              \
                for (int mi = 0; mi < 2; ++mi)                                 \
                    a[mi] = *reinterpret_cast<const short8*>(                  \
                        reinterpret_cast<const char*>(Alds[buf]) +             \
                        (wr * 32 + mi * 16 + lmod) * (LDSTRIDE * 2) + kb2);    \
                _Pragma("unroll")                                              \
                for (int ni = 0; ni < 2; ++ni)                                 \
                    bfr[ni] = *reinterpret_cast<const short8*>(                \
                        reinterpret_cast<const char*>(Wlds[buf]) +             \
                        (wc * 32 + ni * 16 + lmod) * (LDSTRIDE * 2) + kb2);    \
                _Pragma("unroll")                                              \
                for (int mi = 0; mi < 2; ++mi)                                 \
                    _Pragma("unroll")                                          \
                    for (int ni = 0; ni < 2; ++ni)                             \
                        acc[mi][ni] = __builtin_amdgcn_mfma_f32_16x16x32_bf16( \
                            a[mi], bfr[ni], acc[mi][ni], 0, 0, 0);             \
            }                                                                  \
        }

    // Barrier WITHOUT the compiler's vmcnt(0) drain: drain only LDS ops
    // (own ds_writes visible; own ds_reads of the buffer about to be
    // overwritten completed). Global loads stay in flight.
    #define ROLL_BARRIER()                                                     \
        {                                                                      \
            asm volatile("s_waitcnt lgkmcnt(0)" ::: "memory");                 \
            __builtin_amdgcn_s_barrier();                                      \
            asm volatile("" ::: "memory");                                     \
        }

    // ---- prologue: 2 load sets in flight, buffer 0 staged ----
    LOADT(0, 0);
    LOADT(1, 1);
    STORET(0, 0);          // counted wait: set-0's 12 loads (12 stay in flight)
    ROLL_BARRIER();

    // ---- main loop: rolling depth-2 pipeline; vmcnt never drained to 0 ----
    #pragma unroll
    for (int t = 0; t < NSTEP; ++t) {
        if (t + 2 < NSTEP) LOADT(t + 2, t & 1);          // issue early
        COMPUTE(t & 1);
        if (t + 1 < NSTEP) {
            STORET((t + 1) & 1, (t + 1) & 1);            // waits set t+1 only
            ROLL_BARRIER();
        }
    }

    // ---- epilogue: C frag col = lane&15, row = (lane>>4)*4 + r ----
    const int rowbase = bbase + wr * 32 + (ldiv << 2);
    #pragma unroll
    for (int ni = 0; ni < 2; ++ni) {
        const int o  = wc * 32 + ni * 16 + lmod;
        const float bv = bias[g * F_OUT + o];
        #pragma unroll
        for (int mi = 0; mi < 2; ++mi) {
            #pragma unroll
            for (int r = 0; r < 4; ++r) {
                const int brow = rowbase + mi * 16 + r;
                out[(size_t)brow * (G_SZ * F_OUT) + g * F_OUT + o] = acc[mi][ni][r] + bv;
            }
        }
    }
}

extern "C" void kernel_launch(void* const* d_in, const int* in_sizes, int n_in,
                              void* d_out, int out_size, void* d_ws, size_t ws_size,
                              hipStream_t stream) {
    const float* x    = (const float*)d_in[0];
    const int*   idx  = (const int*)d_in[1];
    const float* W    = (const float*)d_in[2];
    const float* bias = (const float*)d_in[3];
    float*       out  = (float*)d_out;

    sparse_linear_kernel<<<dim3(G_SZ * (B_SZ / M_TILE)), dim3(THREADS), 0, stream>>>(
        x, idx, W, bias, out);
}